// Round 5
// baseline (36.440 us; speedup 1.0000x reference)
//
#include <hip/hip_runtime.h>
#include <hip/hip_bf16.h>

#define D 128

// ---------------------------------------------------------------------------
// Note: the reference's c = (a_alpha^T W_alpha) . X[0] cancels in the
// normalization (alpha appears in numerator and denominator), so a_alpha is
// unused and alpha_j = exp(b_w . X[j]) up to a constant factor.
// ---------------------------------------------------------------------------

// Kernel 1 (1 block, 1024 threads): b_w = b_alpha^T @ W_alpha.
__global__ __launch_bounds__(1024) void prep_kernel(
    const float* __restrict__ W_alpha,
    const float* __restrict__ b_alpha,
    float* __restrict__ bw_out)   // [D]
{
    const int t = threadIdx.x;
    const int k = t & 127;        // output column
    const int g = t >> 7;         // 0..7: 16 i-terms each
    __shared__ float bal[D];
    if (t < D) bal[t] = b_alpha[t];
    __syncthreads();

    float bw = 0.f;
    #pragma unroll
    for (int i = g * 16; i < g * 16 + 16; ++i)
        bw = fmaf(bal[i], W_alpha[i * D + k], bw);   // coalesced across k

    __shared__ float rbw[8][D];
    rbw[g][k] = bw;
    __syncthreads();
    if (t < D) {
        float B = 0.f;
        #pragma unroll
        for (int r = 0; r < 8; ++r) B += rbw[r][t];
        bw_out[t] = B;
    }
}

// ---------------------------------------------------------------------------
// Kernel 2 (main pass): branchless streaming of X (requires handling of the
// full 16-row tiles without bounds checks; remainder rows done by block 0).
// Each 32-lane subgroup owns 2 rows/iter, explicit clamped prefetch of the
// next grid-stride tile, running address (no per-iter mul).
// ---------------------------------------------------------------------------
__global__ __launch_bounds__(256, 8) void main_pass_kernel(
    const float* __restrict__ X,
    const float* __restrict__ bw,
    float* __restrict__ partial_wsum,    // [gridDim.x][D]
    float* __restrict__ partial_alpha,   // [gridDim.x]
    int nrows)
{
    const int t    = threadIdx.x;
    const int col4 = t & 31;   // which float4 of the row
    const int rg   = t >> 5;   // row-group 0..7 within the block

    const float4 bwv = reinterpret_cast<const float4*>(bw)[col4];

    float a0 = 0.f, a1 = 0.f, a2 = 0.f, a3 = 0.f;
    float aacc = 0.f;

    const int ftiles = nrows >> 4;          // full 16-row tiles
    const float4* __restrict__ X4 = reinterpret_cast<const float4*>(X);

    int tile = blockIdx.x;
    size_t addr = ((size_t)blockIdx.x * 16 + rg * 2) * 32 + col4;
    const size_t step = (size_t)gridDim.x * 512;   // float4 units per stride

    float4 x0, x1;
    if (tile < ftiles) { x0 = X4[addr]; x1 = X4[addr + 32]; }

    while (tile < ftiles) {
        const int ntile = tile + gridDim.x;
        const size_t naddr = addr + (ntile < ftiles ? step : (size_t)0);
        const float4 n0 = X4[naddr];          // unconditional clamped prefetch
        const float4 n1 = X4[naddr + 32];

        float d0 = fmaf(x0.x, bwv.x, fmaf(x0.y, bwv.y, fmaf(x0.z, bwv.z, x0.w * bwv.w)));
        float d1 = fmaf(x1.x, bwv.x, fmaf(x1.y, bwv.y, fmaf(x1.z, bwv.z, x1.w * bwv.w)));
        #pragma unroll
        for (int m = 16; m >= 1; m >>= 1) {
            d0 += __shfl_xor(d0, m, 64);
            d1 += __shfl_xor(d1, m, 64);
        }
        const float al0 = __expf(d0);
        const float al1 = __expf(d1);
        aacc += al0 + al1;                    // uniform across the 32 lanes
        a0 = fmaf(al0, x0.x, fmaf(al1, x1.x, a0));
        a1 = fmaf(al0, x0.y, fmaf(al1, x1.y, a1));
        a2 = fmaf(al0, x0.z, fmaf(al1, x1.z, a2));
        a3 = fmaf(al0, x0.w, fmaf(al1, x1.w, a3));

        x0 = n0; x1 = n1; addr = naddr; tile = ntile;
    }

    // remainder rows (nrows % 16): block 0 only — dead for N=200000
    const int rem = nrows & 15;
    if (rem && blockIdx.x == 0) {
        const int r0 = (nrows & ~15) + rg * 2;
        if (r0 < nrows) {
            const float4 x0r = X4[(size_t)r0 * 32 + col4];
            const bool v1 = (r0 + 1) < nrows;
            const float4 x1r = v1 ? X4[(size_t)(r0 + 1) * 32 + col4]
                                  : make_float4(0.f, 0.f, 0.f, 0.f);
            float d0 = fmaf(x0r.x, bwv.x, fmaf(x0r.y, bwv.y, fmaf(x0r.z, bwv.z, x0r.w * bwv.w)));
            float d1 = fmaf(x1r.x, bwv.x, fmaf(x1r.y, bwv.y, fmaf(x1r.z, bwv.z, x1r.w * bwv.w)));
            #pragma unroll
            for (int m = 16; m >= 1; m >>= 1) {
                d0 += __shfl_xor(d0, m, 64);
                d1 += __shfl_xor(d1, m, 64);
            }
            const float al0 = __expf(d0);
            const float al1 = v1 ? __expf(d1) : 0.f;
            aacc += al0 + al1;
            a0 = fmaf(al0, x0r.x, fmaf(al1, x1r.x, a0));
            a1 = fmaf(al0, x0r.y, fmaf(al1, x1r.y, a1));
            a2 = fmaf(al0, x0r.z, fmaf(al1, x1r.z, a2));
            a3 = fmaf(al0, x0r.w, fmaf(al1, x1r.w, a3));
        }
    }

    // -------- block reduction (8 row-groups -> one 128-vector) --------
    __shared__ float red[8][32][4];   // 4 KB
    __shared__ float reda[8];
    red[rg][col4][0] = a0;
    red[rg][col4][1] = a1;
    red[rg][col4][2] = a2;
    red[rg][col4][3] = a3;
    if (col4 == 0) reda[rg] = aacc;
    __syncthreads();

    if (t < D) {
        double s = 0.0;
        #pragma unroll
        for (int r = 0; r < 8; ++r) s += (double)red[r][t >> 2][t & 3];
        partial_wsum[(size_t)blockIdx.x * D + t] = (float)s;
    }
    if (t == 0) {
        double s = 0.0;
        #pragma unroll
        for (int r = 0; r < 8; ++r) s += (double)reda[r];
        partial_alpha[blockIdx.x] = (float)s;
    }
}

// ---------------------------------------------------------------------------
// Kernel 3 (NB2 blocks, 512 threads): tree-reduce block partials to float.
// ---------------------------------------------------------------------------
__global__ __launch_bounds__(512) void reduce1_kernel(
    const float* __restrict__ partial_wsum,
    const float* __restrict__ partial_alpha,
    float* __restrict__ mid,      // [NB2][D]
    float* __restrict__ mida,     // [NB2]
    int NB, int NB2)
{
    const int b  = blockIdx.x;
    const int t  = threadIdx.x;
    const int k  = t & 127;
    const int rs = t >> 7;        // 0..3
    const int nper = NB / NB2;

    double s = 0.0;
    for (int j = rs; j < nper; j += 4)
        s += (double)partial_wsum[(size_t)(b + NB2 * j) * D + k];  // coalesced
    __shared__ double red[4][D];  // 4 KB
    red[rs][k] = s;

    __shared__ double reda[64];
    if (t < 64) {
        double sa = 0.0;
        for (int j = t; j < nper; j += 64) sa += (double)partial_alpha[b + NB2 * j];
        reda[t] = sa;
    }
    __syncthreads();

    if (t < D)
        mid[(size_t)b * D + t] = (float)(red[0][t] + red[1][t] + red[2][t] + red[3][t]);
    if (t == 0) {
        double sa = 0.0;
        const int lim = nper < 64 ? nper : 64;
        for (int i = 0; i < lim; ++i) sa += reda[i];
        mida[b] = (float)sa;
    }
}

// ---------------------------------------------------------------------------
// Kernel 4 (1 block, 1024 threads): final reduce, normalize, @ W_sum.
// W_sum (64 KB) is loaded into registers FIRST so its HBM latency hides
// under the mid-reduce, then staged to LDS for the matvec.
// ---------------------------------------------------------------------------
__global__ __launch_bounds__(1024) void final_kernel(
    const float* __restrict__ mid,
    const float* __restrict__ mida,
    const float* __restrict__ W_sum,
    float* __restrict__ out,
    int NB2)
{
    const int t = threadIdx.x;
    const int k = t & 127;
    const int g = t >> 7;     // 0..7

    // --- issue W_sum loads early (4 float4 per thread, coalesced) ---
    const float4* __restrict__ W4 = reinterpret_cast<const float4*>(W_sum);
    float4 w0 = W4[t], w1 = W4[t + 1024], w2 = W4[t + 2048], w3 = W4[t + 3072];

    // --- reduce mid partials while W_sum is in flight ---
    __shared__ float red[8][D];     // 4 KB
    float ws = 0.f;
    #pragma unroll
    for (int j = 0; j < 8; ++j) {
        const int row = g + j * 8;
        if (row < NB2) ws += mid[(size_t)row * D + k];
    }
    red[g][k] = ws;

    __shared__ float reda[64];
    if (t < 64) reda[t] = (t < NB2) ? mida[t] : 0.f;

    // --- stage W_sum to LDS ---
    __shared__ float wls[D * D];    // 64 KB
    float4* wls4 = reinterpret_cast<float4*>(wls);
    wls4[t] = w0; wls4[t + 1024] = w1; wls4[t + 2048] = w2; wls4[t + 3072] = w3;
    __syncthreads();

    __shared__ double asum_sh;
    if (t == 0) {
        double a = 0.0;
        #pragma unroll
        for (int i = 0; i < 64; ++i) a += (double)reda[i];
        asum_sh = a;
    }
    __syncthreads();

    __shared__ float s_sh[D];
    if (t < D) {
        double s = 0.0;
        #pragma unroll
        for (int r = 0; r < 8; ++r) s += (double)red[r][t];
        s_sh[t] = (float)(s / asum_sh);
    }
    __syncthreads();

    // out[j] = sum_k s[k] * W_sum[k][j], split over the 8 groups
    float o = 0.f;
    #pragma unroll
    for (int kk = g * 16; kk < g * 16 + 16; ++kk)
        o = fmaf(s_sh[kk], wls[kk * D + k], o);
    __shared__ float rout[8][D];    // 4 KB
    rout[g][k] = o;
    __syncthreads();
    if (t < D) {
        float s = 0.f;
        #pragma unroll
        for (int r = 0; r < 8; ++r) s += rout[r][t];
        out[t] = s;
    }
}

// ---------------------------------------------------------------------------
extern "C" void kernel_launch(void* const* d_in, const int* in_sizes, int n_in,
                              void* d_out, int out_size, void* d_ws, size_t ws_size,
                              hipStream_t stream) {
    const float* X       = (const float*)d_in[0];
    const float* W_sum   = (const float*)d_in[1];
    const float* W_alpha = (const float*)d_in[2];
    const float* b_alpha = (const float*)d_in[4];
    float* out = (float*)d_out;

    const int nrows = in_sizes[0] / D;   // 200000
    const int NB2 = 64;

    int NB = 2048;
    auto need = [&](int nb) {
        return (size_t)nb * (D + 1) * sizeof(float)     // partials
             + 256
             + (size_t)NB2 * (D + 1) * sizeof(float)    // mid + mida
             + (D + 8) * sizeof(float);
    };
    while (NB > NB2 && need(NB) > ws_size) NB >>= 1;

    char* ws = (char*)d_ws;
    float* partial_wsum  = (float*)ws;
    float* partial_alpha = (float*)(ws + (size_t)NB * D * sizeof(float));
    size_t off = (size_t)NB * (D + 1) * sizeof(float);
    off = (off + 255) & ~(size_t)255;
    float* mid  = (float*)(ws + off);
    float* mida = mid + (size_t)NB2 * D;
    float* bw   = mida + NB2;

    prep_kernel<<<1, 1024, 0, stream>>>(W_alpha, b_alpha, bw);
    main_pass_kernel<<<NB, 256, 0, stream>>>(X, bw, partial_wsum,
                                             partial_alpha, nrows);
    reduce1_kernel<<<NB2, 512, 0, stream>>>(partial_wsum, partial_alpha,
                                            mid, mida, NB, NB2);
    final_kernel<<<1, 1024, 0, stream>>>(mid, mida, W_sum, out, NB2);
}